// Round 1
// baseline (70.165 us; speedup 1.0000x reference)
//
#include <hip/hip_runtime.h>
#include <hip/hip_bf16.h>

// Fused causal self-attention block: B=4096 independent (T=64, C=64) problems.
// One workgroup (256 thr = 4 waves) per batch. All matmuls via
// v_mfma_f32_16x16x32_bf16, fp32 accumulation. Weights pre-converted to bf16
// in d_ws (L2-resident, read as global fragments).

typedef __attribute__((ext_vector_type(8))) short bf16x8;   // 8 bf16 = 4 VGPR
typedef __attribute__((ext_vector_type(4))) float f32x4;    // accum

#define LSTR 72   // LDS row stride in bf16 elems (64 + 8 pad, keeps 16B align, 36-dword stride)
#define LOG2E 1.44269504088896f

__device__ __forceinline__ unsigned short f2b(float f) {
    __hip_bfloat16 h = __float2bfloat16(f);   // RNE
    return __builtin_bit_cast(unsigned short, h);
}

__device__ __forceinline__ bf16x8 ldf(const unsigned short* p) {
    return *(const bf16x8*)p;                 // ds_read_b128 / global_load_dwordx4
}

// ---- pre-kernel: convert the 4 weight matrices fp32 -> bf16 into d_ws ----
__global__ void cvt_w_kernel(const float* __restrict__ wk, const float* __restrict__ wq,
                             const float* __restrict__ wv, const float* __restrict__ wp,
                             unsigned short* __restrict__ dst) {
    int e = blockIdx.x * 256 + threadIdx.x;   // 0..16383
    int m = e >> 12;                          // matrix id (uniform per block: 16 blocks/matrix)
    int off = e & 4095;
    const float* src = (m == 0) ? wk : (m == 1) ? wq : (m == 2) ? wv : wp;
    dst[e] = f2b(src[off]);
}

__global__ __launch_bounds__(256, 4) void attn_fused_kernel(
    const float* __restrict__ x,              // [4096,64,64]
    const unsigned short* __restrict__ wbf,   // bf16: Wk,Wq,Wv,Wp each [64][64] row-major [out][in]
    const float* __restrict__ bp,             // [64]
    float* __restrict__ out)                  // [4096,64,64]
{
    __shared__ unsigned short lA[64 * LSTR];  // x (bf16), later wei (softmaxed P)
    __shared__ unsigned short lB[64 * LSTR];  // q (pre-scaled by 1/8)
    __shared__ unsigned short lC[64 * LSTR];  // k, later attn_out
    __shared__ unsigned short lD[64 * LSTR];  // v^T  [c][t]

    const int tid  = threadIdx.x;
    const int wave = tid >> 6;
    const int lane = tid & 63;
    const int r = lane & 15;   // A-frag row / B-frag col / D col
    const int g = lane >> 4;   // k-group: A/B frag k-base = g*8; D row-base = g*4

    const long b = blockIdx.x;
    const float* xb = x + b * 4096;

    // ---- Phase 1: coalesced load x_b, convert to bf16 row-major in lA ----
    {
        const float4* xv = (const float4*)xb;
        #pragma unroll
        for (int i = 0; i < 4; ++i) {
            int vi = i * 256 + tid;           // float4 index 0..1023
            float4 v = xv[vi];
            int e = vi << 2;
            int row = e >> 6, col = e & 63;
            ushort4 h;
            h.x = f2b(v.x); h.y = f2b(v.y); h.z = f2b(v.z); h.w = f2b(v.w);
            *(ushort4*)(lA + row * LSTR + col) = h;   // 8B aligned
        }
    }
    __syncthreads();

    const unsigned short* Wk = wbf;
    const unsigned short* Wq = wbf + 4096;
    const unsigned short* Wv = wbf + 8192;
    const unsigned short* Wp = wbf + 12288;

    // ---- Phase 2: q = x@Wq^T (scaled 1/8) -> lB ; k = x@Wk^T -> lC ; vT = Wv@x^T -> lD ----
    {
        // A-frags: own 16-row strip of x
        bf16x8 xa0 = ldf(lA + (wave*16 + r) * LSTR + g*8);
        bf16x8 xa1 = ldf(lA + (wave*16 + r) * LSTR + 32 + g*8);

        #pragma unroll
        for (int n = 0; n < 4; ++n) {         // q
            f32x4 acc = {0.f, 0.f, 0.f, 0.f};
            bf16x8 b0 = ldf(Wq + (n*16 + r)*64 + g*8);        // B[k][n] = Wq[n][k] -> row-major read
            bf16x8 b1 = ldf(Wq + (n*16 + r)*64 + 32 + g*8);
            acc = __builtin_amdgcn_mfma_f32_16x16x32_bf16(xa0, b0, acc, 0, 0, 0);
            acc = __builtin_amdgcn_mfma_f32_16x16x32_bf16(xa1, b1, acc, 0, 0, 0);
            #pragma unroll
            for (int j = 0; j < 4; ++j)       // D: row=g*4+j, col=r
                lB[(wave*16 + g*4 + j)*LSTR + n*16 + r] = f2b(acc[j] * 0.125f);
        }
        #pragma unroll
        for (int n = 0; n < 4; ++n) {         // k
            f32x4 acc = {0.f, 0.f, 0.f, 0.f};
            bf16x8 b0 = ldf(Wk + (n*16 + r)*64 + g*8);
            bf16x8 b1 = ldf(Wk + (n*16 + r)*64 + 32 + g*8);
            acc = __builtin_amdgcn_mfma_f32_16x16x32_bf16(xa0, b0, acc, 0, 0, 0);
            acc = __builtin_amdgcn_mfma_f32_16x16x32_bf16(xa1, b1, acc, 0, 0, 0);
            #pragma unroll
            for (int j = 0; j < 4; ++j)
                lC[(wave*16 + g*4 + j)*LSTR + n*16 + r] = f2b(acc[j]);
        }
        // vT = Wv @ x^T : A = Wv rows (output channels = this wave's strip), B[k=c][n=t] = x[t][c]
        bf16x8 wa0 = ldf(Wv + (wave*16 + r)*64 + g*8);
        bf16x8 wa1 = ldf(Wv + (wave*16 + r)*64 + 32 + g*8);
        #pragma unroll
        for (int n = 0; n < 4; ++n) {
            f32x4 acc = {0.f, 0.f, 0.f, 0.f};
            bf16x8 b0 = ldf(lA + (n*16 + r)*LSTR + g*8);      // row-major x serves B of x^T
            bf16x8 b1 = ldf(lA + (n*16 + r)*LSTR + 32 + g*8);
            acc = __builtin_amdgcn_mfma_f32_16x16x32_bf16(wa0, b0, acc, 0, 0, 0);
            acc = __builtin_amdgcn_mfma_f32_16x16x32_bf16(wa1, b1, acc, 0, 0, 0);
            #pragma unroll
            for (int j = 0; j < 4; ++j)       // vT[c = wave*16+g*4+j][t = n*16+r]
                lD[(wave*16 + g*4 + j)*LSTR + n*16 + r] = f2b(acc[j]);
        }
    }
    __syncthreads();

    // ---- Phase 3: wei = softmax(causal(q @ k^T)) -> lA (bf16) ----
    {
        bf16x8 qa0 = ldf(lB + (wave*16 + r)*LSTR + g*8);
        bf16x8 qa1 = ldf(lB + (wave*16 + r)*LSTR + 32 + g*8);
        f32x4 acc[4];
        #pragma unroll
        for (int n = 0; n < 4; ++n) {
            acc[n] = (f32x4){0.f, 0.f, 0.f, 0.f};
            bf16x8 b0 = ldf(lC + (n*16 + r)*LSTR + g*8);      // B[c][s] = k[s][c] -> k row-major
            bf16x8 b1 = ldf(lC + (n*16 + r)*LSTR + 32 + g*8);
            acc[n] = __builtin_amdgcn_mfma_f32_16x16x32_bf16(qa0, b0, acc[n], 0, 0, 0);
            acc[n] = __builtin_amdgcn_mfma_f32_16x16x32_bf16(qa1, b1, acc[n], 0, 0, 0);
        }
        // rows: t = wave*16 + g*4 + j ; cols: S = n*16 + r ; row group = 16 lanes sharing g
        float p[4][4];
        #pragma unroll
        for (int j = 0; j < 4; ++j) {
            const int t = wave*16 + g*4 + j;
            float m = -1e30f;
            #pragma unroll
            for (int n = 0; n < 4; ++n) {
                float vv = ((n*16 + r) <= t) ? acc[n][j] : -1e30f;   // causal mask
                p[n][j] = vv;
                m = fmaxf(m, vv);
            }
            m = fmaxf(m, __shfl_xor(m, 1));
            m = fmaxf(m, __shfl_xor(m, 2));
            m = fmaxf(m, __shfl_xor(m, 4));
            m = fmaxf(m, __shfl_xor(m, 8));
            float s = 0.f;
            #pragma unroll
            for (int n = 0; n < 4; ++n) {
                float e = exp2f((p[n][j] - m) * LOG2E);   // masked -> exp2(-huge) = 0
                p[n][j] = e;
                s += e;
            }
            s += __shfl_xor(s, 1);
            s += __shfl_xor(s, 2);
            s += __shfl_xor(s, 4);
            s += __shfl_xor(s, 8);
            float inv = __builtin_amdgcn_rcpf(s);         // s >= 1 (diagonal), ~1ulp fine for bf16 out
            #pragma unroll
            for (int n = 0; n < 4; ++n)
                lA[(wave*16 + g*4 + j)*LSTR + n*16 + r] = f2b(p[n][j] * inv);
        }
    }
    __syncthreads();   // WAR: phase 4 overwrites lC which phase 3 read

    // ---- Phase 4: attn_out = wei @ v -> lC (bf16) ----
    {
        bf16x8 pa0 = ldf(lA + (wave*16 + r)*LSTR + g*8);
        bf16x8 pa1 = ldf(lA + (wave*16 + r)*LSTR + 32 + g*8);
        #pragma unroll
        for (int n = 0; n < 4; ++n) {
            f32x4 acc = {0.f, 0.f, 0.f, 0.f};
            bf16x8 b0 = ldf(lD + (n*16 + r)*LSTR + g*8);      // B[s][c] = v[s][c] = vT[c][s] row-major
            bf16x8 b1 = ldf(lD + (n*16 + r)*LSTR + 32 + g*8);
            acc = __builtin_amdgcn_mfma_f32_16x16x32_bf16(pa0, b0, acc, 0, 0, 0);
            acc = __builtin_amdgcn_mfma_f32_16x16x32_bf16(pa1, b1, acc, 0, 0, 0);
            #pragma unroll
            for (int j = 0; j < 4; ++j)
                lC[(wave*16 + g*4 + j)*LSTR + n*16 + r] = f2b(acc[j]);
        }
    }
    // no barrier: phase 5 reads only this wave's own 16 rows of lC

    // ---- Phase 5: res = attn_out @ Wp^T + bp -> global ----
    {
        bf16x8 oa0 = ldf(lC + (wave*16 + r)*LSTR + g*8);
        bf16x8 oa1 = ldf(lC + (wave*16 + r)*LSTR + 32 + g*8);
        float* ob = out + b * 4096;
        #pragma unroll
        for (int n = 0; n < 4; ++n) {
            f32x4 acc = {0.f, 0.f, 0.f, 0.f};
            bf16x8 b0 = ldf(Wp + (n*16 + r)*64 + g*8);
            bf16x8 b1 = ldf(Wp + (n*16 + r)*64 + 32 + g*8);
            acc = __builtin_amdgcn_mfma_f32_16x16x32_bf16(oa0, b0, acc, 0, 0, 0);
            acc = __builtin_amdgcn_mfma_f32_16x16x32_bf16(oa1, b1, acc, 0, 0, 0);
            float bias = bp[n*16 + r];
            #pragma unroll
            for (int j = 0; j < 4; ++j)
                ob[(wave*16 + g*4 + j)*64 + n*16 + r] = acc[j] + bias;
        }
    }
}

extern "C" void kernel_launch(void* const* d_in, const int* in_sizes, int n_in,
                              void* d_out, int out_size, void* d_ws, size_t ws_size,
                              hipStream_t stream) {
    const float* x  = (const float*)d_in[0];
    const float* wk = (const float*)d_in[1];
    const float* wq = (const float*)d_in[2];
    const float* wv = (const float*)d_in[3];
    const float* wp = (const float*)d_in[4];
    const float* bp = (const float*)d_in[5];
    unsigned short* wbf = (unsigned short*)d_ws;   // 16384 bf16 = 32 KB

    cvt_w_kernel<<<64, 256, 0, stream>>>(wk, wq, wv, wp, wbf);
    attn_fused_kernel<<<4096, 256, 0, stream>>>(x, wbf, bp, (float*)d_out);
}

// Round 2
// 51.987 us; speedup vs baseline: 1.3497x; 1.3497x over previous
//
#include <hip/hip_runtime.h>
#include <hip/hip_bf16.h>

// Fused causal self-attention: B=4096 independent (T=64, C=64) problems.
// ONE WAVE per batch, 4 waves (4 batches) per 256-thread block, 1024 blocks.
// Zero LDS, zero barriers: the whole chain lives in registers using the
// D-frag/B-frag layout identity for 16x16 MFMA tiles:
//   D-frag (col=lane&15, row=g*4+j)  ==  K=16 B-frag (col=lane&15, k=g*4+e)
//   D-frag as A-frag == transpose of producer.
// Chain: qT=Wq@xT, kT=Wk@xT, v=x@WvT (K=32, x frags from global, dual A/B use)
//        ST=mfma(kT,qT) -> col-softmax in reg (shfl_xor 16,32) -> PT
//        out2T=mfma(v,PT) -> resT=mfma(Wp,out2T)+bias -> float4 stores.

typedef __attribute__((ext_vector_type(8))) short bf16x8;
typedef __attribute__((ext_vector_type(4))) short bf16x4;
typedef __attribute__((ext_vector_type(4))) float f32x4;

#define MFMA32(a, b, c) __builtin_amdgcn_mfma_f32_16x16x32_bf16(a, b, c, 0, 0, 0)
#define MFMA16(a, b, c) __builtin_amdgcn_mfma_f32_16x16x16bf16_1k(a, b, c, 0, 0, 0)
#define LOG2E 1.44269504088896f

__device__ __forceinline__ unsigned short f2b(float f) {
    return __builtin_bit_cast(unsigned short, __float2bfloat16(f));   // RNE
}

__device__ __forceinline__ bf16x4 pack4(f32x4 a, float s) {
    bf16x4 r;
    r[0] = (short)f2b(a[0] * s); r[1] = (short)f2b(a[1] * s);
    r[2] = (short)f2b(a[2] * s); r[3] = (short)f2b(a[3] * s);
    return r;
}

// load 8 consecutive f32 from global, convert to a bf16x8 fragment
__device__ __forceinline__ bf16x8 xfrag(const float* p) {
    const float4 a = *(const float4*)p;
    const float4 b = *(const float4*)(p + 4);
    bf16x8 r;
    r[0] = (short)f2b(a.x); r[1] = (short)f2b(a.y);
    r[2] = (short)f2b(a.z); r[3] = (short)f2b(a.w);
    r[4] = (short)f2b(b.x); r[5] = (short)f2b(b.y);
    r[6] = (short)f2b(b.z); r[7] = (short)f2b(b.w);
    return r;
}

// ---- pre-kernel: convert the 4 weight matrices fp32 -> bf16 into d_ws ----
__global__ void cvt_w_kernel(const float* __restrict__ wk, const float* __restrict__ wq,
                             const float* __restrict__ wv, const float* __restrict__ wp,
                             unsigned short* __restrict__ dst) {
    int e = blockIdx.x * 256 + threadIdx.x;   // 0..16383
    int m = e >> 12;
    int off = e & 4095;
    const float* src = (m == 0) ? wk : (m == 1) ? wq : (m == 2) ? wv : wp;
    dst[e] = f2b(src[off]);
}

__global__ __launch_bounds__(256, 3) void attn_fused_kernel(
    const float* __restrict__ x,              // [4096,64,64] fp32
    const unsigned short* __restrict__ wbf,   // bf16: Wk,Wq,Wv,Wp each [64][64] row-major
    const float* __restrict__ bp,             // [64] fp32
    float* __restrict__ out)                  // [4096,64,64] fp32
{
    const int tid  = threadIdx.x;
    const int lane = tid & 63;
    const int r = lane & 15;      // frag col / A-row index
    const int g = lane >> 4;      // lane group: D rows g*4+j, K16 k = g*4+e, K32 k = g*8+e
    const long b = (long)blockIdx.x * 4 + (tid >> 6);

    const float* xb = x + b * 4096;
    const unsigned short* Wk = wbf;
    const unsigned short* Wq = wbf + 4096;
    const unsigned short* Wv = wbf + 8192;
    const unsigned short* Wp = wbf + 12288;

    // ---- x fragments (K=32): lane holds x[t][ci], t = tt*16+r, ci = ch*32+g*8+e.
    // Serves BOTH as B-frag of (W @ xT) and as A-frag of (x @ WvT).
    bf16x8 xf[4][2];
    #pragma unroll
    for (int tt = 0; tt < 4; ++tt)
        #pragma unroll
        for (int ch = 0; ch < 2; ++ch)
            xf[tt][ch] = xfrag(xb + (tt * 16 + r) * 64 + ch * 32 + g * 8);

    // ---- qT = Wq @ xT (pre-scaled by 1/8), kT = Wk @ xT; keep D-frags as bf16 ----
    bf16x4 qTb[4][4], kTb[4][4];              // [c-tile][t-tile]
    #pragma unroll
    for (int cm = 0; cm < 4; ++cm) {
        bf16x8 a0 = *(const bf16x8*)(Wq + (cm * 16 + r) * 64 + g * 8);
        bf16x8 a1 = *(const bf16x8*)(Wq + (cm * 16 + r) * 64 + 32 + g * 8);
        #pragma unroll
        for (int tt = 0; tt < 4; ++tt) {
            f32x4 acc = {0.f, 0.f, 0.f, 0.f};
            acc = MFMA32(a0, xf[tt][0], acc);
            acc = MFMA32(a1, xf[tt][1], acc);
            qTb[cm][tt] = pack4(acc, 0.125f);
        }
    }
    #pragma unroll
    for (int cm = 0; cm < 4; ++cm) {
        bf16x8 a0 = *(const bf16x8*)(Wk + (cm * 16 + r) * 64 + g * 8);
        bf16x8 a1 = *(const bf16x8*)(Wk + (cm * 16 + r) * 64 + 32 + g * 8);
        #pragma unroll
        for (int tt = 0; tt < 4; ++tt) {
            f32x4 acc = {0.f, 0.f, 0.f, 0.f};
            acc = MFMA32(a0, xf[tt][0], acc);
            acc = MFMA32(a1, xf[tt][1], acc);
            kTb[cm][tt] = pack4(acc, 1.0f);
        }
    }

    // ---- ST[s][t] = sum_c k[s][c] q[t][c] : A = kT-frag (transposed use), B = qT-frag.
    // Causal: tiles with sm > tn are fully masked -> skipped.
    f32x4 st[4][4];                           // [s-tile][t-tile], upper triangle only
    #pragma unroll
    for (int tn = 0; tn < 4; ++tn)
        #pragma unroll
        for (int sm = 0; sm < 4; ++sm) {
            if (sm > tn) continue;
            f32x4 acc = {0.f, 0.f, 0.f, 0.f};
            #pragma unroll
            for (int cm = 0; cm < 4; ++cm)
                acc = MFMA16(kTb[cm][sm], qTb[cm][tn], acc);
            st[sm][tn] = acc;
        }

    // ---- column softmax on ST (per lane: t = tn*16+r fixed, s = sm*16+g*4+j) ----
    bf16x4 ptb[4][4];                         // PT frags, upper triangle
    #pragma unroll
    for (int tn = 0; tn < 4; ++tn) {
        float mx = -1e30f;
        #pragma unroll
        for (int sm = 0; sm < 4; ++sm) {
            if (sm > tn) continue;
            #pragma unroll
            for (int j = 0; j < 4; ++j) {
                float v = st[sm][tn][j];
                if (sm == tn) {               // diagonal tile: mask s > t
                    v = ((g * 4 + j) <= r) ? v : -1e30f;
                    st[sm][tn][j] = v;
                }
                mx = fmaxf(mx, v);
            }
        }
        mx = fmaxf(mx, __shfl_xor(mx, 16));
        mx = fmaxf(mx, __shfl_xor(mx, 32));
        float sum = 0.f;
        #pragma unroll
        for (int sm = 0; sm < 4; ++sm) {
            if (sm > tn) continue;
            #pragma unroll
            for (int j = 0; j < 4; ++j) {
                float e = exp2f((st[sm][tn][j] - mx) * LOG2E);  // masked -> 0
                st[sm][tn][j] = e;
                sum += e;
            }
        }
        sum += __shfl_xor(sum, 16);
        sum += __shfl_xor(sum, 32);
        float inv = __builtin_amdgcn_rcpf(sum);   // sum >= ~1 (diagonal present)
        #pragma unroll
        for (int sm = 0; sm < 4; ++sm) {
            if (sm > tn) continue;
            ptb[sm][tn] = pack4(st[sm][tn], inv);
        }
    }

    // ---- v = x @ WvT : A = x-frag, B = Wv-frag (K=32). D-frags kept as bf16. ----
    bf16x4 vb[4][4];                          // [t(s)-tile][c-tile]
    #pragma unroll
    for (int cm = 0; cm < 4; ++cm) {
        bf16x8 b0 = *(const bf16x8*)(Wv + (cm * 16 + r) * 64 + g * 8);
        bf16x8 b1 = *(const bf16x8*)(Wv + (cm * 16 + r) * 64 + 32 + g * 8);
        #pragma unroll
        for (int tv = 0; tv < 4; ++tv) {
            f32x4 acc = {0.f, 0.f, 0.f, 0.f};
            acc = MFMA32(xf[tv][0], b0, acc);
            acc = MFMA32(xf[tv][1], b1, acc);
            vb[tv][cm] = pack4(acc, 1.0f);
        }
    }

    // ---- out2T[c][t] = sum_s v[s][c] P[t][s] : A = v-frag (transposed use), B = PT-frag.
    // Causal: s-tiles sm > tn contribute zero -> skipped.
    bf16x4 o2b[4][4];                         // [c-tile][t-tile]
    #pragma unroll
    for (int tn = 0; tn < 4; ++tn)
        #pragma unroll
        for (int cm = 0; cm < 4; ++cm) {
            f32x4 acc = {0.f, 0.f, 0.f, 0.f};
            #pragma unroll
            for (int sm = 0; sm < 4; ++sm)
                if (sm <= tn)
                    acc = MFMA16(vb[sm][cm], ptb[sm][tn], acc);
            o2b[cm][tn] = pack4(acc, 1.0f);
        }

    // ---- resT = Wp @ out2T + bias : A = Wp-frag (K=16 from global), B = out2T-frag ----
    float* ob = out + b * 4096;
    #pragma unroll
    for (int om = 0; om < 4; ++om) {
        bf16x4 wpf[4];
        #pragma unroll
        for (int cm = 0; cm < 4; ++cm)
            wpf[cm] = *(const bf16x4*)(Wp + (om * 16 + r) * 64 + cm * 16 + g * 4);
        const float4 bias = *(const float4*)(bp + om * 16 + g * 4);
        #pragma unroll
        for (int tn = 0; tn < 4; ++tn) {
            f32x4 acc = {0.f, 0.f, 0.f, 0.f};
            #pragma unroll
            for (int cm = 0; cm < 4; ++cm)
                acc = MFMA16(wpf[cm], o2b[cm][tn], acc);
            // D_resT: (col t = tn*16+r, row o = om*16+g*4+j) -> res[t][o], j contiguous
            float4 o;
            o.x = acc[0] + bias.x; o.y = acc[1] + bias.y;
            o.z = acc[2] + bias.z; o.w = acc[3] + bias.w;
            *(float4*)(ob + (tn * 16 + r) * 64 + om * 16 + g * 4) = o;
        }
    }
}

extern "C" void kernel_launch(void* const* d_in, const int* in_sizes, int n_in,
                              void* d_out, int out_size, void* d_ws, size_t ws_size,
                              hipStream_t stream) {
    const float* x  = (const float*)d_in[0];
    const float* wk = (const float*)d_in[1];
    const float* wq = (const float*)d_in[2];
    const float* wv = (const float*)d_in[3];
    const float* wp = (const float*)d_in[4];
    const float* bp = (const float*)d_in[5];
    unsigned short* wbf = (unsigned short*)d_ws;   // 16384 bf16 = 32 KB

    cvt_w_kernel<<<64, 256, 0, stream>>>(wk, wq, wv, wp, wbf);
    attn_fused_kernel<<<1024, 256, 0, stream>>>(x, wbf, bp, (float*)d_out);
}